// Round 6
// baseline (329.117 us; speedup 1.0000x reference)
//
#include <hip/hip_runtime.h>

#define N_NODES   100000
#define N_EDGES   1600000
#define DIM       128
#define NUM_LAYERS 3

#define NB   391          // buckets of 256 dst-nodes
#define BCAP 8192         // staging + ss window per bucket (mean 4092 + pads <= ~6200)

typedef __attribute__((ext_vector_type(8))) short short8;
typedef __attribute__((ext_vector_type(4))) float f32x4;

#define MFMA_BF16(acc, a, b) \
    asm("v_mfma_f32_16x16x32_bf16 %0, %1, %2, %0" : "+v"(acc) : "v"(a), "v"(b))

__device__ __forceinline__ unsigned short f2bf(float f) {
    unsigned int u = __builtin_bit_cast(unsigned int, f);
    unsigned int r = (u + 0x7FFFu + ((u >> 16) & 1u)) >> 16;   // RNE
    return (unsigned short)r;
}
__device__ __forceinline__ float bflo(unsigned int p) {
    return __builtin_bit_cast(float, p << 16);
}
__device__ __forceinline__ float bfhi(unsigned int p) {
    return __builtin_bit_cast(float, p & 0xFFFF0000u);
}

// ---------------- prep: f32 -> bf16 ----------------

__global__ void k_cvt(const float* __restrict__ x, unsigned short* __restrict__ xb) {
    int i = blockIdx.x * 256 + threadIdx.x;
    float4 v = ((const float4*)x)[i];
    uint2 o;
    o.x = (unsigned int)f2bf(v.x) | ((unsigned int)f2bf(v.y) << 16);
    o.y = (unsigned int)f2bf(v.z) | ((unsigned int)f2bf(v.w) << 16);
    ((uint2*)xb)[i] = o;
}

__global__ void k_wprep(const float* __restrict__ W1, const float* __restrict__ W2,
                        unsigned short* __restrict__ wb) {
    int o = blockIdx.x * 256 + threadIdx.x;
    int m   = o >> 14;
    int idx = o & 16383;
    int i    = idx & 7;
    int lane = (idx >> 3) & 63;
    int kk   = (idx >> 9) & 3;
    int t    = idx >> 11;
    int k = kk * 32 + (lane >> 4) * 8 + i;
    int n = t * 16 + (lane & 15);
    const float* Wsrc = (m < 3) ? (W1 + (size_t)m * 16384) : (W2 + (size_t)(m - 3) * 16384);
    wb[o] = f2bf(Wsrc[k * 128 + n]);
}

// ---------------- CSR build: bucketed counting sort, lists padded to x8 ----------------

__global__ void k_binit(int* __restrict__ gcur) {
    int i = threadIdx.x;
    if (i < NB) gcur[i] = i * BCAP;
}

__global__ __launch_bounds__(1024) void k_bin(
        const int* __restrict__ src, const int* __restrict__ dst,
        int* __restrict__ gcur, unsigned int* __restrict__ staging) {
    __shared__ int h[NB];
    __shared__ int base[NB];
    int tid = threadIdx.x;
    for (int i = tid; i < NB; i += 1024) h[i] = 0;
    __syncthreads();
    int e0 = blockIdx.x * 16384;
    unsigned int rec[16];
    int bk[16];
    #pragma unroll
    for (int k = 0; k < 16; ++k) {
        int e = e0 + k * 1024 + tid;
        if (e < N_EDGES) {
            int d = dst[e];
            int b = d >> 8;
            bk[k] = b;
            rec[k] = (unsigned int)src[e] | ((unsigned int)(d & 255) << 17);
            atomicAdd(&h[b], 1);
        } else bk[k] = -1;
    }
    __syncthreads();
    for (int i = tid; i < NB; i += 1024) {
        int c = h[i];
        base[i] = (c > 0) ? atomicAdd(&gcur[i], c) : 0;
    }
    __syncthreads();
    for (int i = tid; i < NB; i += 1024) h[i] = 0;
    __syncthreads();
    #pragma unroll
    for (int k = 0; k < 16; ++k) {
        if (bk[k] >= 0) {
            int p = base[bk[k]] + atomicAdd(&h[bk[k]], 1);
            staging[p] = rec[k];
        }
    }
}

// Per bucket: per-node hist -> counts padded to x8 -> bucket-local scan ->
// offs/dege (start/end in the bucket's ss window) -> scatter srcs -> fill pads
// with N_NODES (the all-zero row). No global scan needed.
__global__ __launch_bounds__(256) void k_build(
        const unsigned int* __restrict__ staging, const int* __restrict__ gcur,
        int* __restrict__ offs, int* __restrict__ dege, int* __restrict__ ss) {
    __shared__ int h[256];
    __shared__ int s[256];
    int b = blockIdx.x, t = threadIdx.x;
    int cnt = gcur[b] - b * BCAP;
    const unsigned int* seg = staging + (size_t)b * BCAP;
    h[t] = 0;
    __syncthreads();
    for (int i = t; i < cnt; i += 256) atomicAdd(&h[seg[i] >> 17], 1);
    __syncthreads();
    int c  = h[t];
    int cp = (c + 7) & ~7;            // padded length
    s[t] = cp;
    __syncthreads();
    for (int off = 1; off < 256; off <<= 1) {
        int tmp = 0;
        if (t >= off) tmp = s[t - off];
        __syncthreads();
        if (t >= off) s[t] += tmp;
        __syncthreads();
    }
    int start = b * BCAP + s[t] - cp; // bucket-local window
    int node  = b * 256 + t;
    offs[node] = start;
    dege[node] = start + cp;
    __syncthreads();
    h[t] = start;                      // per-node cursor
    __syncthreads();
    for (int i = t; i < cnt; i += 256) {
        unsigned int r = seg[i];
        int pos = atomicAdd(&h[r >> 17], 1);
        ss[pos] = (int)(r & 0x1FFFFu);
    }
    __syncthreads();
    for (int i = h[t]; i < start + cp; ++i) ss[i] = N_NODES;  // pads -> zero row
}

// ---------------- Fused GIN layer ----------------
// 256 threads = 8 half-wave groups (agg) = 4 waves (MFMA). Block owns 64 nodes.
// Group g aggregates nodes g*8..g*8+7 into hs rows g*8..g*8+7; wave w (groups
// 2w,2w+1) consumes exactly hs rows 16w..16w+15 -> hs is WAVE-PRIVATE: no
// __syncthreads anywhere, and GEMM1's output tile aliases hs (program-order
// LDS dependencies within the wave).

template <int FINAL>
__global__ __launch_bounds__(256) void k_layer(
        const unsigned short* __restrict__ xb,
        const int* __restrict__ offs, const int* __restrict__ dege,
        const int* __restrict__ ss,
        const unsigned short* __restrict__ w1b, const float* __restrict__ b1,
        const unsigned short* __restrict__ w2b, const float* __restrict__ b2,
        unsigned short* __restrict__ xnext, float* __restrict__ outf) {
    __shared__ __align__(16) unsigned short hs[64][136];
    int tid    = threadIdx.x;
    int g      = tid >> 5;
    int lane31 = tid & 31;
    int node0  = blockIdx.x * 64;

    // ---- Phase 1: aggregation (padded lists: pure unroll-8, no remainder) ----
    for (int q = 0; q < 8; ++q) {
        int node = node0 + g * 8 + q;
        float a0 = 0.f, a1 = 0.f, a2 = 0.f, a3 = 0.f;
        if (node < N_NODES) {
            uint2 sv = *(const uint2*)(xb + (size_t)node * DIM + lane31 * 4);
            a0 = bflo(sv.x); a1 = bfhi(sv.x); a2 = bflo(sv.y); a3 = bfhi(sv.y);
            int e   = offs[node];
            int end = dege[node];
            for (; e < end; e += 8) {
                int s0 = ss[e + 0], s1 = ss[e + 1], s2 = ss[e + 2], s3 = ss[e + 3];
                int s4 = ss[e + 4], s5 = ss[e + 5], s6 = ss[e + 6], s7 = ss[e + 7];
                uint2 v0 = *(const uint2*)(xb + (size_t)s0 * DIM + lane31 * 4);
                uint2 v1 = *(const uint2*)(xb + (size_t)s1 * DIM + lane31 * 4);
                uint2 v2 = *(const uint2*)(xb + (size_t)s2 * DIM + lane31 * 4);
                uint2 v3 = *(const uint2*)(xb + (size_t)s3 * DIM + lane31 * 4);
                uint2 v4 = *(const uint2*)(xb + (size_t)s4 * DIM + lane31 * 4);
                uint2 v5 = *(const uint2*)(xb + (size_t)s5 * DIM + lane31 * 4);
                uint2 v6 = *(const uint2*)(xb + (size_t)s6 * DIM + lane31 * 4);
                uint2 v7 = *(const uint2*)(xb + (size_t)s7 * DIM + lane31 * 4);
                a0 += bflo(v0.x) + bflo(v1.x) + bflo(v2.x) + bflo(v3.x)
                    + bflo(v4.x) + bflo(v5.x) + bflo(v6.x) + bflo(v7.x);
                a1 += bfhi(v0.x) + bfhi(v1.x) + bfhi(v2.x) + bfhi(v3.x)
                    + bfhi(v4.x) + bfhi(v5.x) + bfhi(v6.x) + bfhi(v7.x);
                a2 += bflo(v0.y) + bflo(v1.y) + bflo(v2.y) + bflo(v3.y)
                    + bflo(v4.y) + bflo(v5.y) + bflo(v6.y) + bflo(v7.y);
                a3 += bfhi(v0.y) + bfhi(v1.y) + bfhi(v2.y) + bfhi(v3.y)
                    + bfhi(v4.y) + bfhi(v5.y) + bfhi(v6.y) + bfhi(v7.y);
            }
        }
        uint2 o;
        o.x = (unsigned int)f2bf(a0) | ((unsigned int)f2bf(a1) << 16);
        o.y = (unsigned int)f2bf(a2) | ((unsigned int)f2bf(a3) << 16);
        *(uint2*)&hs[g * 8 + q][lane31 * 4] = o;
    }
    // no barrier: hs rows 16w..16w+15 written and read only by wave w

    // ---- Phase 2: MLP ----
    int w    = tid >> 6;
    int lane = tid & 63;
    int lrow = lane & 15;
    int lgrp = lane >> 4;
    int r0   = node0 + w * 16;

    const short8* w1f = (const short8*)w1b;
    const short8* w2f = (const short8*)w2b;

    f32x4 acc[8];
    #pragma unroll
    for (int t = 0; t < 8; ++t) acc[t] = (f32x4){0.f, 0.f, 0.f, 0.f};

    #pragma unroll
    for (int kk = 0; kk < 4; ++kk) {
        short8 a = *(const short8*)&hs[w * 16 + lrow][kk * 32 + lgrp * 8];
        const short8* bp = w1f + kk * 64 + lane;
        #pragma unroll
        for (int t = 0; t < 8; ++t) {
            short8 b = bp[t * 256];
            MFMA_BF16(acc[t], a, b);
        }
    }

    // epilogue1: bias+relu -> bf16, write back into hs (wave-private alias of Ts)
    #pragma unroll
    for (int t = 0; t < 8; ++t) {
        float bb = b1[t * 16 + lrow];
        #pragma unroll
        for (int r = 0; r < 4; ++r) {
            float v = acc[t][r] + bb;
            v = fmaxf(v, 0.f);
            hs[w * 16 + lgrp * 4 + r][t * 16 + lrow] = f2bf(v);
        }
        acc[t] = (f32x4){0.f, 0.f, 0.f, 0.f};
    }

    #pragma unroll
    for (int kk = 0; kk < 4; ++kk) {
        short8 a = *(const short8*)&hs[w * 16 + lrow][kk * 32 + lgrp * 8];
        const short8* bp = w2f + kk * 64 + lane;
        #pragma unroll
        for (int t = 0; t < 8; ++t) {
            short8 b = bp[t * 256];
            MFMA_BF16(acc[t], a, b);
        }
    }

    #pragma unroll
    for (int t = 0; t < 8; ++t) {
        float bb = b2[t * 16 + lrow];
        #pragma unroll
        for (int r = 0; r < 4; ++r) {
            float v = acc[t][r] + bb;
            int row = r0 + lgrp * 4 + r;
            if (row < N_NODES) {
                size_t oi = (size_t)row * DIM + t * 16 + lrow;
                if (FINAL) {
                    outf[oi] = v;
                } else {
                    xnext[oi] = f2bf(fmaxf(v, 0.f));
                }
            }
        }
    }
}

// ---------------- launch ----------------

extern "C" void kernel_launch(void* const* d_in, const int* in_sizes, int n_in,
                              void* d_out, int out_size, void* d_ws, size_t ws_size,
                              hipStream_t stream) {
    const float* x  = (const float*)d_in[0];
    const int*   ei = (const int*)d_in[1];
    const float* W1 = (const float*)d_in[2];
    const float* b1 = (const float*)d_in[3];
    const float* W2 = (const float*)d_in[4];
    const float* b2 = (const float*)d_in[5];
    float* out = (float*)d_out;

    const int* src = ei;
    const int* dst = ei + N_EDGES;

    char* ws = (char*)d_ws;
    int* gcur  = (int*)ws; ws += 2048;
    int* offs  = (int*)ws; ws += 100352 * 4;
    int* dege  = (int*)ws; ws += 100352 * 4;
    int* ss    = (int*)ws; ws += (size_t)NB * BCAP * 4;          // 12.8 MB
    unsigned short* wb  = (unsigned short*)ws; ws += 6 * 16384 * 2;
    unsigned short* xb0 = (unsigned short*)ws; ws += (size_t)(N_NODES + 2) * DIM * 2;
    unsigned short* xb1 = (unsigned short*)ws; ws += (size_t)(N_NODES + 2) * DIM * 2;
    unsigned int* staging = (unsigned int*)xb1;  // 12.8 MB, dead before first k_layer write

    // zero row (index N_NODES) in both ping-pong buffers; pads gather from it
    hipMemsetAsync(xb0 + (size_t)N_NODES * DIM, 0, DIM * 2, stream);
    hipMemsetAsync(xb1 + (size_t)N_NODES * DIM, 0, DIM * 2, stream);

    // prep
    k_cvt  <<<12500, 256, 0, stream>>>(x, xb0);
    k_wprep<<<384,   256, 0, stream>>>(W1, W2, wb);

    // CSR build
    k_binit<<<1, 512, 0, stream>>>(gcur);
    k_bin  <<<98, 1024, 0, stream>>>(src, dst, gcur, staging);
    k_build<<<NB, 256, 0, stream>>>(staging, gcur, offs, dege, ss);

    // 3 fused GIN layers, ping-pong xb0 <-> xb1
    unsigned short* xc = xb0;
    unsigned short* xn = xb1;
    for (int l = 0; l < NUM_LAYERS; ++l) {
        const unsigned short* w1l = wb + (size_t)l * 16384;
        const unsigned short* w2l = wb + (size_t)(3 + l) * 16384;
        const float* b1l = b1 + (size_t)l * DIM;
        const float* b2l = b2 + (size_t)l * DIM;
        if (l < NUM_LAYERS - 1)
            k_layer<0><<<1563, 256, 0, stream>>>(xc, offs, dege, ss, w1l, b1l, w2l, b2l, xn, nullptr);
        else
            k_layer<1><<<1563, 256, 0, stream>>>(xc, offs, dege, ss, w1l, b1l, w2l, b2l, nullptr, out);
        unsigned short* tmp = xc; xc = xn; xn = tmp;
    }
}

// Round 10
// 319.413 us; speedup vs baseline: 1.0304x; 1.0304x over previous
//
#include <hip/hip_runtime.h>

#define N_NODES   100000
#define N_EDGES   1600000
#define DIM       128
#define NUM_LAYERS 3

#define NB   391          // buckets of 256 dst-nodes
#define BCAP 8192         // staging capacity per bucket (mean 4092, sigma 64)
#define NT   13           // src tiles: src>>13 -> 0..12 (tile = 8192 rows = 2 MB bf16)

typedef __attribute__((ext_vector_type(8))) short short8;
typedef __attribute__((ext_vector_type(4))) float f32x4;

#define MFMA_BF16(acc, a, b) \
    asm("v_mfma_f32_16x16x32_bf16 %0, %1, %2, %0" : "+v"(acc) : "v"(a), "v"(b))

__device__ __forceinline__ unsigned short f2bf(float f) {
    unsigned int u = __builtin_bit_cast(unsigned int, f);
    unsigned int r = (u + 0x7FFFu + ((u >> 16) & 1u)) >> 16;   // RNE
    return (unsigned short)r;
}
__device__ __forceinline__ float bflo(unsigned int p) {
    return __builtin_bit_cast(float, p << 16);
}
__device__ __forceinline__ float bfhi(unsigned int p) {
    return __builtin_bit_cast(float, p & 0xFFFF0000u);
}

// ---------------- prep: f32 -> bf16 ----------------

__global__ void k_cvt(const float* __restrict__ x, unsigned short* __restrict__ xb) {
    int i = blockIdx.x * 256 + threadIdx.x;
    float4 v = ((const float4*)x)[i];
    uint2 o;
    o.x = (unsigned int)f2bf(v.x) | ((unsigned int)f2bf(v.y) << 16);
    o.y = (unsigned int)f2bf(v.z) | ((unsigned int)f2bf(v.w) << 16);
    ((uint2*)xb)[i] = o;
}

__global__ void k_wprep(const float* __restrict__ W1, const float* __restrict__ W2,
                        unsigned short* __restrict__ wb) {
    int o = blockIdx.x * 256 + threadIdx.x;
    int m   = o >> 14;
    int idx = o & 16383;
    int i    = idx & 7;
    int lane = (idx >> 3) & 63;
    int kk   = (idx >> 9) & 3;
    int t    = idx >> 11;
    int k = kk * 32 + (lane >> 4) * 8 + i;
    int n = t * 16 + (lane & 15);
    const float* Wsrc = (m < 3) ? (W1 + (size_t)m * 16384) : (W2 + (size_t)(m - 3) * 16384);
    wb[o] = f2bf(Wsrc[k * 128 + n]);
}

// ---------------- CSR build: bucketed counting sort (round-5 base) ----------------

__global__ void k_binit(int* __restrict__ gcur) {
    int i = threadIdx.x;
    if (i < NB) gcur[i] = i * BCAP;
}

__global__ __launch_bounds__(1024) void k_bin(
        const int* __restrict__ src, const int* __restrict__ dst,
        int* __restrict__ gcur, unsigned int* __restrict__ staging) {
    __shared__ int h[NB];
    __shared__ int base[NB];
    int tid = threadIdx.x;
    for (int i = tid; i < NB; i += 1024) h[i] = 0;
    __syncthreads();
    int e0 = blockIdx.x * 16384;
    unsigned int rec[16];
    int bk[16];
    #pragma unroll
    for (int k = 0; k < 16; ++k) {
        int e = e0 + k * 1024 + tid;
        if (e < N_EDGES) {
            int d = dst[e];
            int b = d >> 8;
            bk[k] = b;
            rec[k] = (unsigned int)src[e] | ((unsigned int)(d & 255) << 17);
            atomicAdd(&h[b], 1);
        } else bk[k] = -1;
    }
    __syncthreads();
    for (int i = tid; i < NB; i += 1024) {
        int c = h[i];
        base[i] = (c > 0) ? atomicAdd(&gcur[i], c) : 0;
    }
    __syncthreads();
    for (int i = tid; i < NB; i += 1024) h[i] = 0;
    __syncthreads();
    #pragma unroll
    for (int k = 0; k < 16; ++k) {
        if (bk[k] >= 0) {
            int p = base[bk[k]] + atomicAdd(&h[bk[k]], 1);
            staging[p] = rec[k];
        }
    }
}

__global__ void k_bscan(const int* __restrict__ gcur, int* __restrict__ ebase) {
    __shared__ int s[512];
    int t = threadIdx.x;
    int v = (t < NB) ? (gcur[t] - t * BCAP) : 0;
    s[t] = v;
    __syncthreads();
    for (int off = 1; off < 512; off <<= 1) {
        int tmp = 0;
        if (t >= off) tmp = s[t - off];
        __syncthreads();
        if (t >= off) s[t] += tmp;
        __syncthreads();
    }
    if (t < NB) ebase[t] = s[t] - v;
}

// THE ONE CHANGE vs round 5: scatter each node's compact segment in
// src-tile-major order (per-(node,tile) LDS cursors) for gather locality.
// Same multiset per node segment; offs semantics identical (compact, global).
__global__ __launch_bounds__(256) void k_build(
        const unsigned int* __restrict__ staging, const int* __restrict__ gcur,
        const int* __restrict__ ebase, int* __restrict__ offs, int* __restrict__ ss) {
    __shared__ int h2[256][NT];
    __shared__ int s[256];
    int b = blockIdx.x, t = threadIdx.x;
    int cnt = gcur[b] - b * BCAP;
    const unsigned int* seg = staging + (size_t)b * BCAP;
    #pragma unroll
    for (int i = 0; i < NT; ++i) h2[t][i] = 0;
    __syncthreads();
    for (int i = t; i < cnt; i += 256) {
        unsigned int r = seg[i];
        atomicAdd(&h2[r >> 17][(r & 0x1FFFFu) >> 13], 1);
    }
    __syncthreads();
    int c = 0;
    #pragma unroll
    for (int i = 0; i < NT; ++i) c += h2[t][i];
    s[t] = c;
    __syncthreads();
    for (int off = 1; off < 256; off <<= 1) {
        int tmp = 0;
        if (t >= off) tmp = s[t - off];
        __syncthreads();
        if (t >= off) s[t] += tmp;
        __syncthreads();
    }
    int excl = ebase[b] + s[t] - c;     // global CSR offset for node b*256+t
    offs[b * 256 + t] = excl;
    int run = excl;                     // tile counts -> tile cursors (own row only)
    #pragma unroll
    for (int i = 0; i < NT; ++i) { int cc = h2[t][i]; h2[t][i] = run; run += cc; }
    __syncthreads();
    for (int i = t; i < cnt; i += 256) {
        unsigned int r = seg[i];
        int sv = (int)(r & 0x1FFFFu);
        int pos = atomicAdd(&h2[r >> 17][sv >> 13], 1);
        ss[pos] = sv;
    }
}

// ---------------- Aggregation (round-5 exact): h[i] = x[i] + sum_j x[j] ----------------

__global__ void k_agg(const unsigned short* __restrict__ xb, const int* __restrict__ offs,
                      const int* __restrict__ ss, unsigned short* __restrict__ hb) {
    int g    = threadIdx.x >> 5;
    int lane = threadIdx.x & 31;
    int node = blockIdx.x * 8 + g;
    uint2 sv = *(const uint2*)(xb + (size_t)node * DIM + lane * 4);
    float a0 = bflo(sv.x), a1 = bfhi(sv.x), a2 = bflo(sv.y), a3 = bfhi(sv.y);
    int start = offs[node];
    int end   = offs[node + 1];
    int e = start;
    int n8 = start + ((end - start) & ~7);
    for (; e < n8; e += 8) {
        int s0 = ss[e + 0], s1 = ss[e + 1], s2 = ss[e + 2], s3 = ss[e + 3];
        int s4 = ss[e + 4], s5 = ss[e + 5], s6 = ss[e + 6], s7 = ss[e + 7];
        uint2 v0 = *(const uint2*)(xb + (size_t)s0 * DIM + lane * 4);
        uint2 v1 = *(const uint2*)(xb + (size_t)s1 * DIM + lane * 4);
        uint2 v2 = *(const uint2*)(xb + (size_t)s2 * DIM + lane * 4);
        uint2 v3 = *(const uint2*)(xb + (size_t)s3 * DIM + lane * 4);
        uint2 v4 = *(const uint2*)(xb + (size_t)s4 * DIM + lane * 4);
        uint2 v5 = *(const uint2*)(xb + (size_t)s5 * DIM + lane * 4);
        uint2 v6 = *(const uint2*)(xb + (size_t)s6 * DIM + lane * 4);
        uint2 v7 = *(const uint2*)(xb + (size_t)s7 * DIM + lane * 4);
        a0 += bflo(v0.x) + bflo(v1.x) + bflo(v2.x) + bflo(v3.x)
            + bflo(v4.x) + bflo(v5.x) + bflo(v6.x) + bflo(v7.x);
        a1 += bfhi(v0.x) + bfhi(v1.x) + bfhi(v2.x) + bfhi(v3.x)
            + bfhi(v4.x) + bfhi(v5.x) + bfhi(v6.x) + bfhi(v7.x);
        a2 += bflo(v0.y) + bflo(v1.y) + bflo(v2.y) + bflo(v3.y)
            + bflo(v4.y) + bflo(v5.y) + bflo(v6.y) + bflo(v7.y);
        a3 += bfhi(v0.y) + bfhi(v1.y) + bfhi(v2.y) + bfhi(v3.y)
            + bfhi(v4.y) + bfhi(v5.y) + bfhi(v6.y) + bfhi(v7.y);
    }
    for (; e < end; ++e) {
        int sidx = ss[e];
        uint2 v = *(const uint2*)(xb + (size_t)sidx * DIM + lane * 4);
        a0 += bflo(v.x); a1 += bfhi(v.x); a2 += bflo(v.y); a3 += bfhi(v.y);
    }
    uint2 o;
    o.x = (unsigned int)f2bf(a0) | ((unsigned int)f2bf(a1) << 16);
    o.y = (unsigned int)f2bf(a2) | ((unsigned int)f2bf(a3) << 16);
    *(uint2*)(hb + (size_t)node * DIM + lane * 4) = o;
}

// ---------------- MFMA MLP (round-5 exact, 16 rows/wave — PROVEN) ----------------

template <int FINAL>
__global__ __launch_bounds__(256) void k_mlp(
        const unsigned short* __restrict__ hb,
        const unsigned short* __restrict__ w1b, const float* __restrict__ b1,
        const unsigned short* __restrict__ w2b, const float* __restrict__ b2,
        unsigned short* __restrict__ outb, float* __restrict__ outf) {
    __shared__ unsigned short Ts[4][16][136];
    int tid  = threadIdx.x;
    int w    = tid >> 6;
    int lane = tid & 63;
    int r0   = blockIdx.x * 64 + w * 16;
    bool live = (r0 < N_NODES);
    if (!live) r0 = N_NODES - 16;
    int lrow = lane & 15;
    int lgrp = lane >> 4;

    const short8* hb8  = (const short8*)hb;
    const short8* w1f  = (const short8*)w1b;
    const short8* w2f  = (const short8*)w2b;

    f32x4 acc[8];
    #pragma unroll
    for (int t = 0; t < 8; ++t) acc[t] = (f32x4){0.f, 0.f, 0.f, 0.f};

    #pragma unroll
    for (int kk = 0; kk < 4; ++kk) {
        short8 a = hb8[(size_t)(r0 + lrow) * 16 + kk * 4 + lgrp];
        const short8* bp = w1f + kk * 64 + lane;
        #pragma unroll
        for (int t = 0; t < 8; ++t) {
            short8 b = bp[t * 256];
            MFMA_BF16(acc[t], a, b);
        }
    }

    #pragma unroll
    for (int t = 0; t < 8; ++t) {
        float bb = b1[t * 16 + lrow];
        #pragma unroll
        for (int r = 0; r < 4; ++r) {
            float v = acc[t][r] + bb;
            v = fmaxf(v, 0.f);
            Ts[w][lgrp * 4 + r][t * 16 + lrow] = f2bf(v);
        }
        acc[t] = (f32x4){0.f, 0.f, 0.f, 0.f};
    }
    __syncthreads();

    #pragma unroll
    for (int kk = 0; kk < 4; ++kk) {
        short8 a = *(const short8*)&Ts[w][lrow][kk * 32 + lgrp * 8];
        const short8* bp = w2f + kk * 64 + lane;
        #pragma unroll
        for (int t = 0; t < 8; ++t) {
            short8 b = bp[t * 256];
            MFMA_BF16(acc[t], a, b);
        }
    }

    #pragma unroll
    for (int t = 0; t < 8; ++t) {
        float bb = b2[t * 16 + lrow];
        #pragma unroll
        for (int r = 0; r < 4; ++r) {
            float v = acc[t][r] + bb;
            size_t oi = (size_t)(r0 + lgrp * 4 + r) * DIM + t * 16 + lrow;
            if (FINAL) {
                if (live) outf[oi] = v;
            } else {
                v = fmaxf(v, 0.f);
                if (live) outb[oi] = f2bf(v);
            }
        }
    }
}

// ---------------- launch (round-5 exact) ----------------

extern "C" void kernel_launch(void* const* d_in, const int* in_sizes, int n_in,
                              void* d_out, int out_size, void* d_ws, size_t ws_size,
                              hipStream_t stream) {
    const float* x  = (const float*)d_in[0];
    const int*   ei = (const int*)d_in[1];
    const float* W1 = (const float*)d_in[2];
    const float* b1 = (const float*)d_in[3];
    const float* W2 = (const float*)d_in[4];
    const float* b2 = (const float*)d_in[5];
    float* out = (float*)d_out;

    const int* src = ei;
    const int* dst = ei + N_EDGES;

    char* ws = (char*)d_ws;
    int* gcur  = (int*)ws; ws += 2048;
    int* ebase = (int*)ws; ws += 2048;
    int* offs  = (int*)ws; ws += 100352 * 4;
    int* ss    = (int*)ws; ws += (size_t)N_EDGES * 4;
    unsigned short* wb = (unsigned short*)ws; ws += 6 * 16384 * 2;
    unsigned short* hb = (unsigned short*)ws;
    unsigned int* staging = (unsigned int*)hb;          // aliases hb, dead before first k_agg
    ws += (size_t)N_NODES * DIM * 2;
    unsigned short* xb = (unsigned short*)ws; ws += (size_t)N_NODES * DIM * 2;

    // prep
    k_cvt  <<<12500, 256, 0, stream>>>(x, xb);
    k_wprep<<<384,   256, 0, stream>>>(W1, W2, wb);

    // CSR build: bucketed counting sort (tile-ordered scatter)
    k_binit<<<1, 512, 0, stream>>>(gcur);
    k_bin  <<<98, 1024, 0, stream>>>(src, dst, gcur, staging);
    k_bscan<<<1, 512, 0, stream>>>(gcur, ebase);
    k_build<<<NB, 256, 0, stream>>>(staging, gcur, ebase, offs, ss);

    // 3 GIN layers: agg(xb -> hb), mlp(hb -> xb or out)
    for (int l = 0; l < NUM_LAYERS; ++l) {
        k_agg<<<12500, 256, 0, stream>>>(xb, offs, ss, hb);
        const unsigned short* w1l = wb + (size_t)l * 16384;
        const unsigned short* w2l = wb + (size_t)(3 + l) * 16384;
        const float* b1l = b1 + (size_t)l * DIM;
        const float* b2l = b2 + (size_t)l * DIM;
        if (l < NUM_LAYERS - 1)
            k_mlp<0><<<1563, 256, 0, stream>>>(hb, w1l, b1l, w2l, b2l, xb, nullptr);
        else
            k_mlp<1><<<1563, 256, 0, stream>>>(hb, w1l, b1l, w2l, b2l, nullptr, out);
    }
}

// Round 12
// 312.345 us; speedup vs baseline: 1.0537x; 1.0226x over previous
//
#include <hip/hip_runtime.h>

#define N_NODES   100000
#define N_EDGES   1600000
#define DIM       128
#define NUM_LAYERS 3

#define NB   391          // buckets of 256 dst-nodes
#define BCAP 8192         // staging capacity per bucket (mean 4092, sigma 64)
#define NT   13           // src tiles: src>>13 -> 0..12

typedef __attribute__((ext_vector_type(8))) short short8;
typedef __attribute__((ext_vector_type(4))) float f32x4;

#define MFMA_BF16(acc, a, b) \
    asm("v_mfma_f32_16x16x32_bf16 %0, %1, %2, %0" : "+v"(acc) : "v"(a), "v"(b))

__device__ __forceinline__ unsigned short f2bf(float f) {
    unsigned int u = __builtin_bit_cast(unsigned int, f);
    unsigned int r = (u + 0x7FFFu + ((u >> 16) & 1u)) >> 16;   // RNE
    return (unsigned short)r;
}
__device__ __forceinline__ float bflo(unsigned int p) {
    return __builtin_bit_cast(float, p << 16);
}
__device__ __forceinline__ float bfhi(unsigned int p) {
    return __builtin_bit_cast(float, p & 0xFFFF0000u);
}

// ---------------- prep: f32 -> bf16 ----------------

__global__ void k_cvt(const float* __restrict__ x, unsigned short* __restrict__ xb) {
    int i = blockIdx.x * 256 + threadIdx.x;
    float4 v = ((const float4*)x)[i];
    uint2 o;
    o.x = (unsigned int)f2bf(v.x) | ((unsigned int)f2bf(v.y) << 16);
    o.y = (unsigned int)f2bf(v.z) | ((unsigned int)f2bf(v.w) << 16);
    ((uint2*)xb)[i] = o;
}

__global__ void k_wprep(const float* __restrict__ W1, const float* __restrict__ W2,
                        unsigned short* __restrict__ wb) {
    int o = blockIdx.x * 256 + threadIdx.x;
    int m   = o >> 14;
    int idx = o & 16383;
    int i    = idx & 7;
    int lane = (idx >> 3) & 63;
    int kk   = (idx >> 9) & 3;
    int t    = idx >> 11;
    int k = kk * 32 + (lane >> 4) * 8 + i;
    int n = t * 16 + (lane & 15);
    const float* Wsrc = (m < 3) ? (W1 + (size_t)m * 16384) : (W2 + (size_t)(m - 3) * 16384);
    wb[o] = f2bf(Wsrc[k * 128 + n]);
}

// ---------------- CSR build (round-10 exact, PASSED) ----------------

__global__ void k_binit(int* __restrict__ gcur) {
    int i = threadIdx.x;
    if (i < NB) gcur[i] = i * BCAP;
}

__global__ __launch_bounds__(1024) void k_bin(
        const int* __restrict__ src, const int* __restrict__ dst,
        int* __restrict__ gcur, unsigned int* __restrict__ staging) {
    __shared__ int h[NB];
    __shared__ int base[NB];
    int tid = threadIdx.x;
    for (int i = tid; i < NB; i += 1024) h[i] = 0;
    __syncthreads();
    int e0 = blockIdx.x * 16384;
    unsigned int rec[16];
    int bk[16];
    #pragma unroll
    for (int k = 0; k < 16; ++k) {
        int e = e0 + k * 1024 + tid;
        if (e < N_EDGES) {
            int d = dst[e];
            int b = d >> 8;
            bk[k] = b;
            rec[k] = (unsigned int)src[e] | ((unsigned int)(d & 255) << 17);
            atomicAdd(&h[b], 1);
        } else bk[k] = -1;
    }
    __syncthreads();
    for (int i = tid; i < NB; i += 1024) {
        int c = h[i];
        base[i] = (c > 0) ? atomicAdd(&gcur[i], c) : 0;
    }
    __syncthreads();
    for (int i = tid; i < NB; i += 1024) h[i] = 0;
    __syncthreads();
    #pragma unroll
    for (int k = 0; k < 16; ++k) {
        if (bk[k] >= 0) {
            int p = base[bk[k]] + atomicAdd(&h[bk[k]], 1);
            staging[p] = rec[k];
        }
    }
}

__global__ void k_bscan(const int* __restrict__ gcur, int* __restrict__ ebase) {
    __shared__ int s[512];
    int t = threadIdx.x;
    int v = (t < NB) ? (gcur[t] - t * BCAP) : 0;
    s[t] = v;
    __syncthreads();
    for (int off = 1; off < 512; off <<= 1) {
        int tmp = 0;
        if (t >= off) tmp = s[t - off];
        __syncthreads();
        if (t >= off) s[t] += tmp;
        __syncthreads();
    }
    if (t < NB) ebase[t] = s[t] - v;
}

__global__ __launch_bounds__(256) void k_build(
        const unsigned int* __restrict__ staging, const int* __restrict__ gcur,
        const int* __restrict__ ebase, int* __restrict__ offs, int* __restrict__ ss) {
    __shared__ int h2[256][NT];
    __shared__ int s[256];
    int b = blockIdx.x, t = threadIdx.x;
    int cnt = gcur[b] - b * BCAP;
    const unsigned int* seg = staging + (size_t)b * BCAP;
    #pragma unroll
    for (int i = 0; i < NT; ++i) h2[t][i] = 0;
    __syncthreads();
    for (int i = t; i < cnt; i += 256) {
        unsigned int r = seg[i];
        atomicAdd(&h2[r >> 17][(r & 0x1FFFFu) >> 13], 1);
    }
    __syncthreads();
    int c = 0;
    #pragma unroll
    for (int i = 0; i < NT; ++i) c += h2[t][i];
    s[t] = c;
    __syncthreads();
    for (int off = 1; off < 256; off <<= 1) {
        int tmp = 0;
        if (t >= off) tmp = s[t - off];
        __syncthreads();
        if (t >= off) s[t] += tmp;
        __syncthreads();
    }
    int excl = ebase[b] + s[t] - c;
    offs[b * 256 + t] = excl;
    int run = excl;
    #pragma unroll
    for (int i = 0; i < NT; ++i) { int cc = h2[t][i]; h2[t][i] = run; run += cc; }
    __syncthreads();
    for (int i = t; i < cnt; i += 256) {
        unsigned int r = seg[i];
        int sv = (int)(r & 0x1FFFFu);
        int pos = atomicAdd(&h2[r >> 17][sv >> 13], 1);
        ss[pos] = sv;
    }
}

// ---------------- Aggregation: masked 16-batches, no serial tail ----------------
// 8 nodes / 256-thread block; 32 lanes per node, one uint2 (4 bf16) per lane.
// Each batch: 16 clamped index loads -> 16 independent row gathers -> masked adds.
// Clamp q = min(p, end-1) stays >= start (loop body only entered when start < end),
// so ss reads stay inside this node's segment; masked values are zeroed.

__global__ void k_agg(const unsigned short* __restrict__ xb, const int* __restrict__ offs,
                      const int* __restrict__ ss, unsigned short* __restrict__ hb) {
    int g    = threadIdx.x >> 5;
    int lane = threadIdx.x & 31;
    int node = blockIdx.x * 8 + g;
    uint2 sv = *(const uint2*)(xb + (size_t)node * DIM + lane * 4);
    float a0 = bflo(sv.x), a1 = bfhi(sv.x), a2 = bflo(sv.y), a3 = bfhi(sv.y);
    int start = offs[node];
    int end   = offs[node + 1];
    for (int e = start; e < end; e += 16) {
        int  sdx[16];
        #pragma unroll
        for (int j = 0; j < 16; ++j) {
            int p = e + j;
            sdx[j] = ss[p < end ? p : end - 1];
        }
        uint2 vv[16];
        #pragma unroll
        for (int j = 0; j < 16; ++j)
            vv[j] = *(const uint2*)(xb + (size_t)sdx[j] * DIM + lane * 4);
        #pragma unroll
        for (int j = 0; j < 16; ++j) {
            bool m = (e + j) < end;
            unsigned int vx = m ? vv[j].x : 0u;
            unsigned int vy = m ? vv[j].y : 0u;
            a0 += bflo(vx); a1 += bfhi(vx);
            a2 += bflo(vy); a3 += bfhi(vy);
        }
    }
    uint2 o;
    o.x = (unsigned int)f2bf(a0) | ((unsigned int)f2bf(a1) << 16);
    o.y = (unsigned int)f2bf(a2) | ((unsigned int)f2bf(a3) << 16);
    *(uint2*)(hb + (size_t)node * DIM + lane * 4) = o;
}

// ---------------- MFMA MLP (round-5/10 exact, 16 rows/wave — PROVEN, FROZEN) ----------------

template <int FINAL>
__global__ __launch_bounds__(256) void k_mlp(
        const unsigned short* __restrict__ hb,
        const unsigned short* __restrict__ w1b, const float* __restrict__ b1,
        const unsigned short* __restrict__ w2b, const float* __restrict__ b2,
        unsigned short* __restrict__ outb, float* __restrict__ outf) {
    __shared__ unsigned short Ts[4][16][136];
    int tid  = threadIdx.x;
    int w    = tid >> 6;
    int lane = tid & 63;
    int r0   = blockIdx.x * 64 + w * 16;
    bool live = (r0 < N_NODES);
    if (!live) r0 = N_NODES - 16;
    int lrow = lane & 15;
    int lgrp = lane >> 4;

    const short8* hb8  = (const short8*)hb;
    const short8* w1f  = (const short8*)w1b;
    const short8* w2f  = (const short8*)w2b;

    f32x4 acc[8];
    #pragma unroll
    for (int t = 0; t < 8; ++t) acc[t] = (f32x4){0.f, 0.f, 0.f, 0.f};

    #pragma unroll
    for (int kk = 0; kk < 4; ++kk) {
        short8 a = hb8[(size_t)(r0 + lrow) * 16 + kk * 4 + lgrp];
        const short8* bp = w1f + kk * 64 + lane;
        #pragma unroll
        for (int t = 0; t < 8; ++t) {
            short8 b = bp[t * 256];
            MFMA_BF16(acc[t], a, b);
        }
    }

    #pragma unroll
    for (int t = 0; t < 8; ++t) {
        float bb = b1[t * 16 + lrow];
        #pragma unroll
        for (int r = 0; r < 4; ++r) {
            float v = acc[t][r] + bb;
            v = fmaxf(v, 0.f);
            Ts[w][lgrp * 4 + r][t * 16 + lrow] = f2bf(v);
        }
        acc[t] = (f32x4){0.f, 0.f, 0.f, 0.f};
    }
    __syncthreads();

    #pragma unroll
    for (int kk = 0; kk < 4; ++kk) {
        short8 a = *(const short8*)&Ts[w][lrow][kk * 32 + lgrp * 8];
        const short8* bp = w2f + kk * 64 + lane;
        #pragma unroll
        for (int t = 0; t < 8; ++t) {
            short8 b = bp[t * 256];
            MFMA_BF16(acc[t], a, b);
        }
    }

    #pragma unroll
    for (int t = 0; t < 8; ++t) {
        float bb = b2[t * 16 + lrow];
        #pragma unroll
        for (int r = 0; r < 4; ++r) {
            float v = acc[t][r] + bb;
            size_t oi = (size_t)(r0 + lgrp * 4 + r) * DIM + t * 16 + lrow;
            if (FINAL) {
                if (live) outf[oi] = v;
            } else {
                v = fmaxf(v, 0.f);
                if (live) outb[oi] = f2bf(v);
            }
        }
    }
}

// ---------------- launch (round-10 exact) ----------------

extern "C" void kernel_launch(void* const* d_in, const int* in_sizes, int n_in,
                              void* d_out, int out_size, void* d_ws, size_t ws_size,
                              hipStream_t stream) {
    const float* x  = (const float*)d_in[0];
    const int*   ei = (const int*)d_in[1];
    const float* W1 = (const float*)d_in[2];
    const float* b1 = (const float*)d_in[3];
    const float* W2 = (const float*)d_in[4];
    const float* b2 = (const float*)d_in[5];
    float* out = (float*)d_out;

    const int* src = ei;
    const int* dst = ei + N_EDGES;

    char* ws = (char*)d_ws;
    int* gcur  = (int*)ws; ws += 2048;
    int* ebase = (int*)ws; ws += 2048;
    int* offs  = (int*)ws; ws += 100352 * 4;
    int* ss    = (int*)ws; ws += (size_t)N_EDGES * 4;
    unsigned short* wb = (unsigned short*)ws; ws += 6 * 16384 * 2;
    unsigned short* hb = (unsigned short*)ws;
    unsigned int* staging = (unsigned int*)hb;          // aliases hb, dead before first k_agg
    ws += (size_t)N_NODES * DIM * 2;
    unsigned short* xb = (unsigned short*)ws; ws += (size_t)N_NODES * DIM * 2;

    // prep
    k_cvt  <<<12500, 256, 0, stream>>>(x, xb);
    k_wprep<<<384,   256, 0, stream>>>(W1, W2, wb);

    // CSR build
    k_binit<<<1, 512, 0, stream>>>(gcur);
    k_bin  <<<98, 1024, 0, stream>>>(src, dst, gcur, staging);
    k_bscan<<<1, 512, 0, stream>>>(gcur, ebase);
    k_build<<<NB, 256, 0, stream>>>(staging, gcur, ebase, offs, ss);

    // 3 GIN layers: agg(xb -> hb), mlp(hb -> xb or out)
    for (int l = 0; l < NUM_LAYERS; ++l) {
        k_agg<<<12500, 256, 0, stream>>>(xb, offs, ss, hb);
        const unsigned short* w1l = wb + (size_t)l * 16384;
        const unsigned short* w2l = wb + (size_t)(3 + l) * 16384;
        const float* b1l = b1 + (size_t)l * DIM;
        const float* b2l = b2 + (size_t)l * DIM;
        if (l < NUM_LAYERS - 1)
            k_mlp<0><<<1563, 256, 0, stream>>>(hb, w1l, b1l, w2l, b2l, xb, nullptr);
        else
            k_mlp<1><<<1563, 256, 0, stream>>>(hb, w1l, b1l, w2l, b2l, nullptr, out);
    }
}

// Round 13
// 295.532 us; speedup vs baseline: 1.1136x; 1.0569x over previous
//
#include <hip/hip_runtime.h>

#define N_NODES   100000
#define N_EDGES   1600000
#define DIM       128
#define NUM_LAYERS 3

#define NB   391          // buckets of 256 dst-nodes
#define BCAP 8192         // staging capacity per bucket (mean 4092, sigma 64)
#define NT   13           // src tiles: src>>13 -> 0..12

typedef __attribute__((ext_vector_type(8))) short short8;
typedef __attribute__((ext_vector_type(4))) float f32x4;

// Hazard-safe MFMA: the compiler inserts required wait-states for the builtin.
// (Theory: prior inline-asm MFMA lacked hazard handling -> every k_mlp
// restructure failed with schedule-dependent corruption.)
#define MFMA_BF16(acc, a, b) \
    acc = __builtin_amdgcn_mfma_f32_16x16x32_bf16(a, b, acc, 0, 0, 0)

__device__ __forceinline__ unsigned short f2bf(float f) {
    unsigned int u = __builtin_bit_cast(unsigned int, f);
    unsigned int r = (u + 0x7FFFu + ((u >> 16) & 1u)) >> 16;   // RNE
    return (unsigned short)r;
}
__device__ __forceinline__ float bflo(unsigned int p) {
    return __builtin_bit_cast(float, p << 16);
}
__device__ __forceinline__ float bfhi(unsigned int p) {
    return __builtin_bit_cast(float, p & 0xFFFF0000u);
}

// ---------------- prep: f32 -> bf16 ----------------

__global__ void k_cvt(const float* __restrict__ x, unsigned short* __restrict__ xb) {
    int i = blockIdx.x * 256 + threadIdx.x;
    float4 v = ((const float4*)x)[i];
    uint2 o;
    o.x = (unsigned int)f2bf(v.x) | ((unsigned int)f2bf(v.y) << 16);
    o.y = (unsigned int)f2bf(v.z) | ((unsigned int)f2bf(v.w) << 16);
    ((uint2*)xb)[i] = o;
}

__global__ void k_wprep(const float* __restrict__ W1, const float* __restrict__ W2,
                        unsigned short* __restrict__ wb) {
    int o = blockIdx.x * 256 + threadIdx.x;
    int m   = o >> 14;
    int idx = o & 16383;
    int i    = idx & 7;
    int lane = (idx >> 3) & 63;
    int kk   = (idx >> 9) & 3;
    int t    = idx >> 11;
    int k = kk * 32 + (lane >> 4) * 8 + i;
    int n = t * 16 + (lane & 15);
    const float* Wsrc = (m < 3) ? (W1 + (size_t)m * 16384) : (W2 + (size_t)(m - 3) * 16384);
    wb[o] = f2bf(Wsrc[k * 128 + n]);
}

// ---------------- CSR build (round-10/12 exact, PASSED) ----------------

__global__ void k_binit(int* __restrict__ gcur) {
    int i = threadIdx.x;
    if (i < NB) gcur[i] = i * BCAP;
}

__global__ __launch_bounds__(1024) void k_bin(
        const int* __restrict__ src, const int* __restrict__ dst,
        int* __restrict__ gcur, unsigned int* __restrict__ staging) {
    __shared__ int h[NB];
    __shared__ int base[NB];
    int tid = threadIdx.x;
    for (int i = tid; i < NB; i += 1024) h[i] = 0;
    __syncthreads();
    int e0 = blockIdx.x * 16384;
    unsigned int rec[16];
    int bk[16];
    #pragma unroll
    for (int k = 0; k < 16; ++k) {
        int e = e0 + k * 1024 + tid;
        if (e < N_EDGES) {
            int d = dst[e];
            int b = d >> 8;
            bk[k] = b;
            rec[k] = (unsigned int)src[e] | ((unsigned int)(d & 255) << 17);
            atomicAdd(&h[b], 1);
        } else bk[k] = -1;
    }
    __syncthreads();
    for (int i = tid; i < NB; i += 1024) {
        int c = h[i];
        base[i] = (c > 0) ? atomicAdd(&gcur[i], c) : 0;
    }
    __syncthreads();
    for (int i = tid; i < NB; i += 1024) h[i] = 0;
    __syncthreads();
    #pragma unroll
    for (int k = 0; k < 16; ++k) {
        if (bk[k] >= 0) {
            int p = base[bk[k]] + atomicAdd(&h[bk[k]], 1);
            staging[p] = rec[k];
        }
    }
}

__global__ void k_bscan(const int* __restrict__ gcur, int* __restrict__ ebase) {
    __shared__ int s[512];
    int t = threadIdx.x;
    int v = (t < NB) ? (gcur[t] - t * BCAP) : 0;
    s[t] = v;
    __syncthreads();
    for (int off = 1; off < 512; off <<= 1) {
        int tmp = 0;
        if (t >= off) tmp = s[t - off];
        __syncthreads();
        if (t >= off) s[t] += tmp;
        __syncthreads();
    }
    if (t < NB) ebase[t] = s[t] - v;
}

__global__ __launch_bounds__(256) void k_build(
        const unsigned int* __restrict__ staging, const int* __restrict__ gcur,
        const int* __restrict__ ebase, int* __restrict__ offs, int* __restrict__ ss) {
    __shared__ int h2[256][NT];
    __shared__ int s[256];
    int b = blockIdx.x, t = threadIdx.x;
    int cnt = gcur[b] - b * BCAP;
    const unsigned int* seg = staging + (size_t)b * BCAP;
    #pragma unroll
    for (int i = 0; i < NT; ++i) h2[t][i] = 0;
    __syncthreads();
    for (int i = t; i < cnt; i += 256) {
        unsigned int r = seg[i];
        atomicAdd(&h2[r >> 17][(r & 0x1FFFFu) >> 13], 1);
    }
    __syncthreads();
    int c = 0;
    #pragma unroll
    for (int i = 0; i < NT; ++i) c += h2[t][i];
    s[t] = c;
    __syncthreads();
    for (int off = 1; off < 256; off <<= 1) {
        int tmp = 0;
        if (t >= off) tmp = s[t - off];
        __syncthreads();
        if (t >= off) s[t] += tmp;
        __syncthreads();
    }
    int excl = ebase[b] + s[t] - c;
    offs[b * 256 + t] = excl;
    int run = excl;
    #pragma unroll
    for (int i = 0; i < NT; ++i) { int cc = h2[t][i]; h2[t][i] = run; run += cc; }
    __syncthreads();
    for (int i = t; i < cnt; i += 256) {
        unsigned int r = seg[i];
        int sv = (int)(r & 0x1FFFFu);
        int pos = atomicAdd(&h2[r >> 17][sv >> 13], 1);
        ss[pos] = sv;
    }
}

// ---------------- Aggregation (round-12 exact, at its ~3 TB/s wall) ----------------

__global__ void k_agg(const unsigned short* __restrict__ xb, const int* __restrict__ offs,
                      const int* __restrict__ ss, unsigned short* __restrict__ hb) {
    int g    = threadIdx.x >> 5;
    int lane = threadIdx.x & 31;
    int node = blockIdx.x * 8 + g;
    uint2 sv = *(const uint2*)(xb + (size_t)node * DIM + lane * 4);
    float a0 = bflo(sv.x), a1 = bfhi(sv.x), a2 = bflo(sv.y), a3 = bfhi(sv.y);
    int start = offs[node];
    int end   = offs[node + 1];
    for (int e = start; e < end; e += 16) {
        int  sdx[16];
        #pragma unroll
        for (int j = 0; j < 16; ++j) {
            int p = e + j;
            sdx[j] = ss[p < end ? p : end - 1];
        }
        uint2 vv[16];
        #pragma unroll
        for (int j = 0; j < 16; ++j)
            vv[j] = *(const uint2*)(xb + (size_t)sdx[j] * DIM + lane * 4);
        #pragma unroll
        for (int j = 0; j < 16; ++j) {
            bool m = (e + j) < end;
            unsigned int vx = m ? vv[j].x : 0u;
            unsigned int vy = m ? vv[j].y : 0u;
            a0 += bflo(vx); a1 += bfhi(vx);
            a2 += bflo(vy); a3 += bfhi(vy);
        }
    }
    uint2 o;
    o.x = (unsigned int)f2bf(a0) | ((unsigned int)f2bf(a1) << 16);
    o.y = (unsigned int)f2bf(a2) | ((unsigned int)f2bf(a3) << 16);
    *(uint2*)(hb + (size_t)node * DIM + lane * 4) = o;
}

// ---------------- MFMA MLP: 16 rows/wave, LDS-staged weights, builtin MFMA ----------------
// r11 structure retried under the hazard fix: W1 staged in LDS -> GEMM1 ->
// barrier -> W2 restaged over same 32 KB -> GEMM2. Fragment order identical to
// the proven kernel; per-block L2 weight traffic 512 KB -> 64 KB.

template <int FINAL>
__global__ __launch_bounds__(256) void k_mlp(
        const unsigned short* __restrict__ hb,
        const unsigned short* __restrict__ w1b, const float* __restrict__ b1,
        const unsigned short* __restrict__ w2b, const float* __restrict__ b2,
        unsigned short* __restrict__ outb, float* __restrict__ outf) {
    __shared__ __align__(16) unsigned short Ws[16384];   // 32 KB: W1, then W2
    __shared__ __align__(16) unsigned short Ts[4][16][136];
    int tid  = threadIdx.x;
    int w    = tid >> 6;
    int lane = tid & 63;
    int r0   = blockIdx.x * 64 + w * 16;
    bool live = (r0 < N_NODES);
    if (!live) r0 = N_NODES - 16;
    int lrow = lane & 15;
    int lgrp = lane >> 4;

    const short8* hb8 = (const short8*)hb;
    const short8* wsf = (const short8*)Ws;

    // prefetch this wave's A fragments before staging (latency overlap)
    short8 a_pre[4];
    #pragma unroll
    for (int kk = 0; kk < 4; ++kk)
        a_pre[kk] = hb8[(size_t)(r0 + lrow) * 16 + kk * 4 + lgrp];

    {   // stage W1: 2048 uint4 by 256 threads x 8
        const uint4* srcp = (const uint4*)w1b;
        uint4* dstp = (uint4*)Ws;
        #pragma unroll
        for (int i = 0; i < 8; ++i) dstp[tid + 256 * i] = srcp[tid + 256 * i];
    }
    __syncthreads();

    f32x4 acc[8];
    #pragma unroll
    for (int t = 0; t < 8; ++t) acc[t] = (f32x4){0.f, 0.f, 0.f, 0.f};

    #pragma unroll
    for (int kk = 0; kk < 4; ++kk) {
        short8 a = a_pre[kk];
        const short8* bp = wsf + kk * 64 + lane;
        #pragma unroll
        for (int t = 0; t < 8; ++t) {
            short8 b = bp[t * 256];
            MFMA_BF16(acc[t], a, b);
        }
    }

    #pragma unroll
    for (int t = 0; t < 8; ++t) {
        float bb = b1[t * 16 + lrow];
        #pragma unroll
        for (int r = 0; r < 4; ++r) {
            float v = acc[t][r] + bb;
            v = fmaxf(v, 0.f);
            Ts[w][lgrp * 4 + r][t * 16 + lrow] = f2bf(v);
        }
        acc[t] = (f32x4){0.f, 0.f, 0.f, 0.f};
    }
    __syncthreads();   // all GEMM1 reads of Ws done; Ts written

    {   // stage W2 over the same LDS
        const uint4* srcp = (const uint4*)w2b;
        uint4* dstp = (uint4*)Ws;
        #pragma unroll
        for (int i = 0; i < 8; ++i) dstp[tid + 256 * i] = srcp[tid + 256 * i];
    }
    __syncthreads();

    #pragma unroll
    for (int kk = 0; kk < 4; ++kk) {
        short8 a = *(const short8*)&Ts[w][lrow][kk * 32 + lgrp * 8];
        const short8* bp = wsf + kk * 64 + lane;
        #pragma unroll
        for (int t = 0; t < 8; ++t) {
            short8 b = bp[t * 256];
            MFMA_BF16(acc[t], a, b);
        }
    }

    #pragma unroll
    for (int t = 0; t < 8; ++t) {
        float bb = b2[t * 16 + lrow];
        #pragma unroll
        for (int r = 0; r < 4; ++r) {
            float v = acc[t][r] + bb;
            size_t oi = (size_t)(r0 + lgrp * 4 + r) * DIM + t * 16 + lrow;
            if (FINAL) {
                if (live) outf[oi] = v;
            } else {
                v = fmaxf(v, 0.f);
                if (live) outb[oi] = f2bf(v);
            }
        }
    }
}

// ---------------- launch (round-12 exact) ----------------

extern "C" void kernel_launch(void* const* d_in, const int* in_sizes, int n_in,
                              void* d_out, int out_size, void* d_ws, size_t ws_size,
                              hipStream_t stream) {
    const float* x  = (const float*)d_in[0];
    const int*   ei = (const int*)d_in[1];
    const float* W1 = (const float*)d_in[2];
    const float* b1 = (const float*)d_in[3];
    const float* W2 = (const float*)d_in[4];
    const float* b2 = (const float*)d_in[5];
    float* out = (float*)d_out;

    const int* src = ei;
    const int* dst = ei + N_EDGES;

    char* ws = (char*)d_ws;
    int* gcur  = (int*)ws; ws += 2048;
    int* ebase = (int*)ws; ws += 2048;
    int* offs  = (int*)ws; ws += 100352 * 4;
    int* ss    = (int*)ws; ws += (size_t)N_EDGES * 4;
    unsigned short* wb = (unsigned short*)ws; ws += 6 * 16384 * 2;
    unsigned short* hb = (unsigned short*)ws;
    unsigned int* staging = (unsigned int*)hb;          // aliases hb, dead before first k_agg
    ws += (size_t)N_NODES * DIM * 2;
    unsigned short* xb = (unsigned short*)ws; ws += (size_t)N_NODES * DIM * 2;

    // prep
    k_cvt  <<<12500, 256, 0, stream>>>(x, xb);
    k_wprep<<<384,   256, 0, stream>>>(W1, W2, wb);

    // CSR build
    k_binit<<<1, 512, 0, stream>>>(gcur);
    k_bin  <<<98, 1024, 0, stream>>>(src, dst, gcur, staging);
    k_bscan<<<1, 512, 0, stream>>>(gcur, ebase);
    k_build<<<NB, 256, 0, stream>>>(staging, gcur, ebase, offs, ss);

    // 3 GIN layers: agg(xb -> hb), mlp(hb -> xb or out)
    for (int l = 0; l < NUM_LAYERS; ++l) {
        k_agg<<<12500, 256, 0, stream>>>(xb, offs, ss, hb);
        const unsigned short* w1l = wb + (size_t)l * 16384;
        const unsigned short* w2l = wb + (size_t)(3 + l) * 16384;
        const float* b1l = b1 + (size_t)l * DIM;
        const float* b2l = b2 + (size_t)l * DIM;
        if (l < NUM_LAYERS - 1)
            k_mlp<0><<<1563, 256, 0, stream>>>(hb, w1l, b1l, w2l, b2l, xb, nullptr);
        else
            k_mlp<1><<<1563, 256, 0, stream>>>(hb, w1l, b1l, w2l, b2l, nullptr, out);
    }
}